// Round 19
// baseline (60.216 us; speedup 1.0000x reference)
//
#include <hip/hip_runtime.h>
#include <math.h>

#define B_    2
#define C_    512
#define H_    64
#define W_    32
#define S_    2048
#define QKC_  576
#define INNER_ 512
#define NH_   8
#define HD_   64
#define TWO_PI_ 6.283185307179586f

typedef __attribute__((ext_vector_type(8))) short bfrag;
typedef __attribute__((ext_vector_type(4))) float ffrag;
typedef __attribute__((ext_vector_type(16))) float f16v;

typedef __attribute__((address_space(1))) const unsigned int as1_u32;
typedef __attribute__((address_space(3))) unsigned int as3_u32;

__device__ __forceinline__ ushort f2bf(float f) {
    unsigned u = __builtin_bit_cast(unsigned, f);
    unsigned r = (u + 0x7FFFu + ((u >> 16) & 1u)) >> 16;
    return (ushort)r;
}

__device__ __forceinline__ f16v zero16() {
    f16v z;
    #pragma unroll
    for (int i = 0; i < 16; i++) z[i] = 0.f;
    return z;
}

#define GLD(gp_, lp_) __builtin_amdgcn_global_load_lds((as1_u32*)(gp_), (as3_u32*)(lp_), 16, 0, 0)
#define EXPA(dst_, x_) asm("v_exp_f32 %0, %1" : "=v"(dst_) : "v"(x_))
#define SC_LOG2E 0.18033688011f   /* 0.125 * log2(e) */

// ---------------- fused pre-pass: X build (transpose+emb) AND 4 weight transposes ----------
__global__ void k_pre(const float* __restrict__ hid,
                      const float* __restrict__ Wq, const float* __restrict__ Wk,
                      const float* __restrict__ Wv, const float* __restrict__ Wo,
                      ushort* __restrict__ X,
                      ushort* __restrict__ Wqt, ushort* __restrict__ Wkt,
                      ushort* __restrict__ Wvt, ushort* __restrict__ Wot) {
    __shared__ float t[32][33];
    int tx = threadIdx.x, ty = threadIdx.y;
    int z = blockIdx.z;
    if (z < 2) {
        int b = z;
        int s0 = blockIdx.x * 32, c0 = blockIdx.y * 32;
        if (c0 < 512) {
            t[ty][tx] = hid[((size_t)b * C_ + (c0 + ty)) * S_ + s0 + tx];
            __syncthreads();
            X[((size_t)(b * S_ + s0 + ty)) * QKC_ + c0 + tx] = f2bf(t[tx][ty]);
        } else {
            int c = c0 - 512 + tx;
            int s = s0 + ty;
            int h = s >> 5, w = s & 31;
            float val;
            if (c < 32) {
                int f = c >> 1;
                int n = h * 16 + f;
                float lx = (n == 0) ? -2.0f : log2f((float)n);
                float arg = lx * (float)(f + 1);
                val = (c & 1) ? sinf(arg) : cosf(arg);
            } else {
                int tt = (c - 32) >> 1;
                float theta = ((float)tt + 0.5f) * (float)(w * 16 + tt) * (TWO_PI_ / 512.0f);
                val = (c & 1) ? sinf(theta) : cosf(theta);
            }
            X[(size_t)(b * S_ + s) * QKC_ + c0 + tx] = f2bf(val);
        }
    } else {
        int idx = blockIdx.y * 64 + blockIdx.x;      // 0..1151
        int z4 = idx / 288, rem = idx % 288;
        int k0 = (rem % 18) * 32, n0 = (rem / 18) * 32;
        const float* W; ushort* Wt; int K;
        if (z4 == 0)      { W = Wq; Wt = Wqt; K = QKC_; }
        else if (z4 == 1) { W = Wk; Wt = Wkt; K = QKC_; }
        else if (z4 == 2) { W = Wv; Wt = Wvt; K = C_; }
        else              { W = Wo; Wt = Wot; K = INNER_; }
        if (k0 >= K) return;
        t[ty][tx] = W[(size_t)(k0 + ty) * 512 + n0 + tx];
        __syncthreads();
        Wt[(size_t)(n0 + ty) * K + k0 + tx] = f2bf(t[tx][ty]);
    }
}

// ---------------- fused QKV GEMM (Q pre-scaled by 0.125*log2e) ----------------
#define GSTAGE(buf_, k0_) {                                                   \
    _Pragma("unroll")                                                         \
    for (int i_ = 0; i_ < 6; i_++)                                            \
        GLD(gp[i_] + (k0_), tl + (buf_) * 12288 + lo[i_]); }

__global__ __launch_bounds__(256, 3) void k_qkv(const ushort* __restrict__ X,
                                                const ushort* __restrict__ Wqt,
                                                const ushort* __restrict__ Wkt,
                                                const ushort* __restrict__ Wvt,
                                                ushort* __restrict__ Qb,
                                                ushort* __restrict__ Kpk,
                                                ushort* __restrict__ Vpk) {
    __shared__ ushort __attribute__((aligned(16))) tl[2 * 12288];   // 48 KB

    int tid = threadIdx.x;
    int l = tid & 63, wv = tid >> 6;
    int wr = wv >> 1, wc = wv & 1;
    int bid = blockIdx.x;
    int lgc = (bid & 7) * 96 + (bid >> 3);
    int bx = lgc % 24, by = lgc / 24;
    int n0 = bx * 64, m0 = by * 128;
    int sel = n0 >> 9, n0l = n0 & 511;
    const ushort* Bt = (sel == 0) ? Wqt : (sel == 1) ? Wkt : Wvt;
    const int K = (sel < 2) ? QKC_ : C_;
    const int nst = K >> 6;
    int l15 = l & 15, lg = l >> 4;
    int swz = l15 & 7;

    const ushort* gp[6];
    unsigned lo[6];
    {
        int rsub = l >> 3;
        int clog = (l & 7) ^ rsub;
        #pragma unroll
        for (int i = 0; i < 6; i++) {
            int c = wv * 6 + i;
            lo[i] = c * 512;
            if (c < 16) gp[i] = X  + (size_t)(m0  + c * 8        + rsub) * QKC_ + clog * 8;
            else        gp[i] = Bt + (size_t)(n0l + (c - 16) * 8 + rsub) * K    + clog * 8;
        }
    }

    ffrag acc[4][2];
    #pragma unroll
    for (int i = 0; i < 4; i++)
        #pragma unroll
        for (int j = 0; j < 2; j++) acc[i][j] = (ffrag){0.f, 0.f, 0.f, 0.f};

    GSTAGE(0, 0);
    int cur = 0;
    for (int kt = 0; kt < nst; kt++) {
        __syncthreads();
        if (kt + 1 < nst) GSTAGE(cur ^ 1, (kt + 1) * 64);
        const ushort* As = tl + cur * 12288;
        const ushort* Bs = As + 8192;
        #pragma unroll
        for (int ks = 0; ks < 2; ks++) {
            int cl = ks * 4 + lg;
            int ch = (cl ^ swz) * 8;
            bfrag af[4], bf[2];
            #pragma unroll
            for (int mi = 0; mi < 4; mi++)
                af[mi] = *(const bfrag*)(As + (wr * 64 + mi * 16 + l15) * 64 + ch);
            #pragma unroll
            for (int nj = 0; nj < 2; nj++)
                bf[nj] = *(const bfrag*)(Bs + (wc * 32 + nj * 16 + l15) * 64 + ch);
            #pragma unroll
            for (int mi = 0; mi < 4; mi++)
                #pragma unroll
                for (int nj = 0; nj < 2; nj++)
                    acc[mi][nj] = __builtin_amdgcn_mfma_f32_16x16x32_bf16(af[mi], bf[nj], acc[mi][nj], 0, 0, 0);
        }
        cur ^= 1;
    }

    if (sel == 0) {
        #pragma unroll
        for (int mi = 0; mi < 4; mi++)
            #pragma unroll
            for (int nj = 0; nj < 2; nj++)
                #pragma unroll
                for (int r = 0; r < 4; r++) {
                    int row = m0 + wr * 64 + mi * 16 + lg * 4 + r;
                    int col = n0l + wc * 32 + nj * 16 + l15;
                    Qb[(size_t)row * INNER_ + col] = f2bf(acc[mi][nj][r] * SC_LOG2E);
                }
    } else {
        ushort (*Ct)[136] = (ushort(*)[136])tl;
        __syncthreads();
        #pragma unroll
        for (int mi = 0; mi < 4; mi++)
            #pragma unroll
            for (int nj = 0; nj < 2; nj++)
                #pragma unroll
                for (int r = 0; r < 4; r++)
                    Ct[wc * 32 + nj * 16 + l15][wr * 64 + mi * 16 + lg * 4 + r] = f2bf(acc[mi][nj][r]);
        __syncthreads();
        int pair = (m0 >> 11) * 8 + (n0l >> 6);
        int kvb0 = (m0 & 2047) >> 5;
        if (sel == 1) {
            #pragma unroll
            for (int p = 0; p < 4; p++) {
                int cid = tid + p * 256;
                int sl = cid >> 7, kv = cid & 127;
                bfrag tmp;
                #pragma unroll
                for (int j = 0; j < 8; j++) tmp[j] = (short)Ct[sl * 8 + j][kv];
                ushort* dst = Kpk + ((size_t)((pair * 64 + kvb0 + (kv >> 5)) * 8 + sl)) * 256 + (kv & 31) * 8;
                *(uint4*)dst = __builtin_bit_cast(uint4, tmp);
            }
        } else {
            #pragma unroll
            for (int p = 0; p < 4; p++) {
                int cid = tid + p * 256;
                int d = cid >> 4, mc = cid & 15;
                uint4 v = *(uint4*)&Ct[d][mc * 8];
                ushort* dst = Vpk + ((size_t)((pair * 64 + kvb0 + (mc >> 2)) * 4 + (mc & 3))) * 512 + d * 8;
                *(uint4*)dst = v;
            }
        }
    }
}

// ---------------- output GEMM + bias + transpose + residual (unchanged) ----------------
__global__ __launch_bounds__(256, 2) void k_og(const ushort* __restrict__ Ob,
                                               const ushort* __restrict__ Wot,
                                               const float* __restrict__ bias,
                                               const float* __restrict__ hid,
                                               float* __restrict__ out) {
    __shared__ ushort __attribute__((aligned(16))) tl[2 * 12288];

    int tid = threadIdx.x;
    int l = tid & 63, wv = tid >> 6;
    int wr = wv >> 1, wc = wv & 1;
    int bid = blockIdx.x;
    int lgc = (bid & 7) * 32 + (bid >> 3);
    int bx = lgc & 7, by = lgc >> 3;
    int n0 = bx * 64, m0 = by * 128;
    int l15 = l & 15, lg = l >> 4;
    int swz = l15 & 7;

    const ushort* gp[6];
    unsigned lo[6];
    {
        int rsub = l >> 3;
        int clog = (l & 7) ^ rsub;
        #pragma unroll
        for (int i = 0; i < 6; i++) {
            int c = wv * 6 + i;
            lo[i] = c * 512;
            if (c < 16) gp[i] = Ob  + (size_t)(m0 + c * 8        + rsub) * INNER_ + clog * 8;
            else        gp[i] = Wot + (size_t)(n0 + (c - 16) * 8 + rsub) * INNER_ + clog * 8;
        }
    }

    ffrag acc[4][2];
    #pragma unroll
    for (int i = 0; i < 4; i++)
        #pragma unroll
        for (int j = 0; j < 2; j++) acc[i][j] = (ffrag){0.f, 0.f, 0.f, 0.f};

    GSTAGE(0, 0);
    int cur = 0;
    for (int kt = 0; kt < 8; kt++) {
        __syncthreads();
        if (kt < 7) GSTAGE(cur ^ 1, (kt + 1) * 64);
        const ushort* As = tl + cur * 12288;
        const ushort* Bs = As + 8192;
        #pragma unroll
        for (int ks = 0; ks < 2; ks++) {
            int cl = ks * 4 + lg;
            int ch = (cl ^ swz) * 8;
            bfrag af[4], bf[2];
            #pragma unroll
            for (int mi = 0; mi < 4; mi++)
                af[mi] = *(const bfrag*)(As + (wr * 64 + mi * 16 + l15) * 64 + ch);
            #pragma unroll
            for (int nj = 0; nj < 2; nj++)
                bf[nj] = *(const bfrag*)(Bs + (wc * 32 + nj * 16 + l15) * 64 + ch);
            #pragma unroll
            for (int mi = 0; mi < 4; mi++)
                #pragma unroll
                for (int nj = 0; nj < 2; nj++)
                    acc[mi][nj] = __builtin_amdgcn_mfma_f32_16x16x32_bf16(af[mi], bf[nj], acc[mi][nj], 0, 0, 0);
        }
        cur ^= 1;
    }

    float (*Cf)[129] = (float(*)[129])tl;
    float bv[2];
    #pragma unroll
    for (int nj = 0; nj < 2; nj++) bv[nj] = bias[n0 + wc * 32 + nj * 16 + l15];
    __syncthreads();
    #pragma unroll
    for (int mi = 0; mi < 4; mi++)
        #pragma unroll
        for (int nj = 0; nj < 2; nj++)
            #pragma unroll
            for (int r = 0; r < 4; r++)
                Cf[wc * 32 + nj * 16 + l15][wr * 64 + mi * 16 + lg * 4 + r] = acc[mi][nj][r] + bv[nj];
    __syncthreads();
    int b = m0 >> 11, s0m = m0 & 2047;
    #pragma unroll
    for (int p = 0; p < 8; p++) {
        int f = p * 256 + tid;
        int c = f >> 5, sq = (f & 31) * 4;
        size_t o = (((size_t)(b * 512 + n0 + c)) << 11) + s0m + sq;
        float4 hv = *(const float4*)(hid + o);
        float4 cv = *(float4*)&Cf[c][sq];
        cv.x += hv.x; cv.y += hv.y; cv.z += hv.z; cv.w += hv.w;
        *(float4*)(out + o) = cv;
    }
}

// ---------------- flash attention: r12 loop, 64q blocks, 8-way KV split ----------------
// grid 512 x 512 thr = 8 waves (sp 0..7). Block = 64 q rows x full KV; wave = dual
// q-group (A: rows 0-31, B: rows 32-63) x EIGHTH KV (8 iters of 32 kv). Same register
// structure as round 12 (128 VGPR, no spill) but LDS only 35.8 KB via 4-pass epilogue
// -> TWO blocks truly co-resident per CU (grid 512 = 2/CU) = 4 waves/SIMD, so wave A's
// exp (VALU) interleaves with wave B's MFMA.
#define CVTPK(dst, a, b) asm("v_cvt_pk_bf16_f32 %0, %1, %2" : "=v"(dst) : "v"(a), "v"(b))
#define SWAP32(a, b)     asm("v_permlane32_swap_b32 %0, %1" : "+v"(a), "+v"(b))

#define KLOAD(dst_, kt_) {                                                    \
    const ushort* g_ = kpb + (size_t)(kt_) * 2048 + kro;                      \
    _Pragma("unroll")                                                         \
    for (int ks_ = 0; ks_ < 4; ks_++) dst_[ks_] = *(const bfrag*)(g_ + ks_ * 512); }

#define VLOAD(dst_, kt_) {                                                    \
    const ushort* g_ = vpb + (size_t)(kt_) * 2048 + vro;                      \
    dst_[0] = *(const bfrag*)(g_);                                            \
    dst_[1] = *(const bfrag*)(g_ + 256);                                      \
    dst_[2] = *(const bfrag*)(g_ + 1024);                                     \
    dst_[3] = *(const bfrag*)(g_ + 1280); }

#define PVHALF(sf_, vf_, a0_, a1_) {                                          \
    _Pragma("unroll")                                                         \
    for (int s = 0; s < 2; s++) {                                             \
        unsigned A0, B0, A1, B1;                                              \
        CVTPK(A0, sf_[s * 8 + 0], sf_[s * 8 + 1]); CVTPK(B0, sf_[s * 8 + 4], sf_[s * 8 + 5]); \
        SWAP32(A0, B0);                                                       \
        CVTPK(A1, sf_[s * 8 + 2], sf_[s * 8 + 3]); CVTPK(B1, sf_[s * 8 + 6], sf_[s * 8 + 7]); \
        SWAP32(A1, B1);                                                       \
        uint4 u_; u_.x = A0; u_.y = A1; u_.z = B0; u_.w = B1;                 \
        bfrag pa_ = __builtin_bit_cast(bfrag, u_);                            \
        a0_ = __builtin_amdgcn_mfma_f32_32x32x16_bf16(vf_[s * 2],     pa_, a0_, 0, 0, 0); \
        a1_ = __builtin_amdgcn_mfma_f32_32x32x16_bf16(vf_[s * 2 + 1], pa_, a1_, 0, 0, 0); \
    } }

#define ABODY(kf_, vf_) {                                                     \
    __builtin_amdgcn_s_setprio(1);                                            \
    f16v sfA = __builtin_amdgcn_mfma_f32_32x32x16_bf16(kf_[0], qfA[0], fz, 0, 0, 0); \
    f16v sfB = __builtin_amdgcn_mfma_f32_32x32x16_bf16(kf_[0], qfB[0], fz, 0, 0, 0); \
    _Pragma("unroll")                                                         \
    for (int ks = 1; ks < 4; ks++) {                                          \
        sfA = __builtin_amdgcn_mfma_f32_32x32x16_bf16(kf_[ks], qfA[ks], sfA, 0, 0, 0); \
        sfB = __builtin_amdgcn_mfma_f32_32x32x16_bf16(kf_[ks], qfB[ks], sfB, 0, 0, 0); \
    }                                                                         \
    __builtin_amdgcn_s_setprio(0);                                            \
    float a0 = 0.f, a1 = 0.f, a2 = 0.f, a3 = 0.f;                             \
    float b0 = 0.f, b1 = 0.f, b2 = 0.f, b3 = 0.f;                             \
    _Pragma("unroll")                                                         \
    for (int j = 0; j < 4; j++) {                                             \
        float pA0; EXPA(pA0, sfA[j]);      sfA[j] = pA0;      a0 += pA0;      \
        float pA1; EXPA(pA1, sfA[j + 4]);  sfA[j + 4] = pA1;  a1 += pA1;      \
        float pA2; EXPA(pA2, sfA[j + 8]);  sfA[j + 8] = pA2;  a2 += pA2;      \
        float pA3; EXPA(pA3, sfA[j + 12]); sfA[j + 12] = pA3; a3 += pA3;      \
        float pB0; EXPA(pB0, sfB[j]);      sfB[j] = pB0;      b0 += pB0;      \
        float pB1; EXPA(pB1, sfB[j + 4]);  sfB[j + 4] = pB1;  b1 += pB1;      \
        float pB2; EXPA(pB2, sfB[j + 8]);  sfB[j + 8] = pB2;  b2 += pB2;      \
        float pB3; EXPA(pB3, sfB[j + 12]); sfB[j + 12] = pB3; b3 += pB3;      \
    }                                                                         \
    lA += (a0 + a1) + (a2 + a3);                                              \
    lB += (b0 + b1) + (b2 + b3);                                              \
    __builtin_amdgcn_s_setprio(1);                                            \
    PVHALF(sfA, vf_, accA0, accA1);                                           \
    PVHALF(sfB, vf_, accB0, accB1);                                           \
    __builtin_amdgcn_s_setprio(0); }

// dump one acc quadrant: 32 d x 32 q per wave slot
#define DUMPC(acc_) {                                                         \
    float* cw = cmb + wvid * 1056;                                            \
    _Pragma("unroll")                                                         \
    for (int j = 0; j < 16; j++) {                                            \
        int d0 = (j & 3) + 8 * (j >> 2) + 4 * hi;                             \
        cw[d0 * 33 + l31] = acc_[j];                                          \
    } }

// combine one (group g_, d-half dh_): 512 thr = 32 q x 16 d-pairs
#define COMBC(g_, dh_) {                                                      \
    int qq = tid >> 4, dp = tid & 15;                                         \
    float lt = 0.f;                                                           \
    _Pragma("unroll")                                                         \
    for (int s8 = 0; s8 < 8; s8++) lt += lsh[(s8 * 2 + (g_)) * 32 + qq];      \
    float inv = 1.0f / lt;                                                    \
    float s0 = 0.f, s1 = 0.f;                                                 \
    _Pragma("unroll")                                                         \
    for (int s8 = 0; s8 < 8; s8++) {                                          \
        s0 += cmb[s8 * 1056 + (dp * 2)     * 33 + qq];                        \
        s1 += cmb[s8 * 1056 + (dp * 2 + 1) * 33 + qq];                        \
    }                                                                         \
    unsigned pk = (unsigned)f2bf(s0 * inv) | ((unsigned)f2bf(s1 * inv) << 16);\
    *(unsigned*)(Ob + (size_t)(brow + (g_) * 32 + qq) * INNER_ + hoff         \
                 + (dh_) * 32 + dp * 2) = pk; }

__global__ __launch_bounds__(512, 2) void k_attn(const ushort* __restrict__ Qf,
                                                 const ushort* __restrict__ Kpk,
                                                 const ushort* __restrict__ Vpk,
                                                 ushort* __restrict__ Ob) {
    __shared__ __attribute__((aligned(16))) char smem[35840];   // 35.8 KB -> 2 blocks/CU
    float* cmb = (float*)smem;                   // per pass: [8 waves][32 d][33] f32
    float* lsh = (float*)(smem + 33792);         // [8 sp][2 g][32 q]

    const int id  = blockIdx.x;                  // 0..511
    const int xcd = id & 7, wi = id >> 3;        // wi 0..63
    const int pair = xcd * 2 + (wi >> 5);
    const int qt   = wi & 31;                    // 64-row q tile
    const int hd = pair & 7, b = pair >> 3;

    const int tid = threadIdx.x;
    const int l = tid & 63, wvid = tid >> 6;     // wvid = sp (0..7)
    const int sp = wvid;
    const int l31 = l & 31, hi = l >> 5;
    const int hoff = hd * HD_;
    const int brow = b * S_ + qt * 64;

    bfrag qfA[4], qfB[4];
    {
        const ushort* qpA = Qf + (size_t)(brow + l31) * INNER_ + hoff + hi * 8;
        const ushort* qpB = qpA + (size_t)32 * INNER_;
        #pragma unroll
        for (int ks = 0; ks < 4; ks++) {
            qfA[ks] = *(const bfrag*)(qpA + ks * 16);
            qfB[ks] = *(const bfrag*)(qpB + ks * 16);
        }
    }

    const ushort* kpb = Kpk + ((size_t)pair * 64 + sp * 8) * 2048;
    const ushort* vpb = Vpk + ((size_t)pair * 64 + sp * 8) * 2048;
    const int kro = hi * 256 + l31 * 8;
    const int vro = hi * 512 + l31 * 8;

    const f16v fz = zero16();
    float lA = 0.f, lB = 0.f;
    f16v accA0 = fz, accA1 = fz;
    f16v accB0 = fz, accB1 = fz;

    bfrag kc[4], vc[4], kn[4], vn[4];
    KLOAD(kc, 0); VLOAD(vc, 0);

    for (int it = 0; it < 8; it += 2) {
        if (it + 1 < 8) { KLOAD(kn, it + 1); VLOAD(vn, it + 1); }
        ABODY(kc, vc);
        if (it + 2 < 8) { KLOAD(kc, it + 2); VLOAD(vc, it + 2); }
        ABODY(kn, vn);
    }

    lA += __shfl_xor(lA, 32);
    lB += __shfl_xor(lB, 32);

    if (hi == 0) {
        lsh[(sp * 2 + 0) * 32 + l31] = lA;
        lsh[(sp * 2 + 1) * 32 + l31] = lB;
    }

    // 4-pass epilogue: (g=A, d 0..31), (A, 32..63), (B, 0..31), (B, 32..63)
    DUMPC(accA0);
    __syncthreads();
    COMBC(0, 0);
    __syncthreads();
    DUMPC(accA1);
    __syncthreads();
    COMBC(0, 1);
    __syncthreads();
    DUMPC(accB0);
    __syncthreads();
    COMBC(1, 0);
    __syncthreads();
    DUMPC(accB1);
    __syncthreads();
    COMBC(1, 1);
}

extern "C" void kernel_launch(void* const* d_in, const int* in_sizes, int n_in,
                              void* d_out, int out_size, void* d_ws, size_t ws_size,
                              hipStream_t stream) {
    const float* hid  = (const float*)d_in[0];
    const float* Wq   = (const float*)d_in[1];
    const float* Wk   = (const float*)d_in[2];
    const float* Wv   = (const float*)d_in[3];
    const float* Wout = (const float*)d_in[4];
    const float* bout = (const float*)d_in[5];
    float* out = (float*)d_out;

    const int M = B_ * S_;   // 4096
    char* w = (char*)d_ws;
    ushort* X    = (ushort*)w;                    w += (size_t)M * QKC_ * 2;
    ushort* Qb   = (ushort*)w;                    w += (size_t)M * INNER_ * 2;
    ushort* Kpk  = (ushort*)w;                    w += (size_t)M * INNER_ * 2;   // packed
    ushort* Vpk  = (ushort*)w;                    w += (size_t)M * INNER_ * 2;   // packed
    ushort* Ob   = (ushort*)w;                    w += (size_t)M * INNER_ * 2;
    ushort* Wqt  = (ushort*)w;                    w += (size_t)INNER_ * QKC_ * 2;
    ushort* Wkt  = (ushort*)w;                    w += (size_t)INNER_ * QKC_ * 2;
    ushort* Wvt  = (ushort*)w;                    w += (size_t)INNER_ * C_ * 2;
    ushort* Wot  = (ushort*)w;                    w += (size_t)C_ * INNER_ * 2;

    k_pre<<<dim3(64, 18, 3), dim3(32, 32), 0, stream>>>(hid, Wq, Wk, Wv, Wout,
                                                        X, Wqt, Wkt, Wvt, Wot);

    k_qkv<<<dim3(768), 256, 0, stream>>>(X, Wqt, Wkt, Wvt, Qb, Kpk, Vpk);

    k_attn<<<dim3(512), 512, 0, stream>>>(Qb, Kpk, Vpk, Ob);

    k_og<<<dim3(256), 256, 0, stream>>>(Ob, Wot, bout, hid, out);
}

// Round 20
// 56.136 us; speedup vs baseline: 1.0727x; 1.0727x over previous
//
#include <hip/hip_runtime.h>
#include <math.h>

#define B_    2
#define C_    512
#define H_    64
#define W_    32
#define S_    2048
#define QKC_  576
#define INNER_ 512
#define NH_   8
#define HD_   64
#define TWO_PI_ 6.283185307179586f

typedef __attribute__((ext_vector_type(8))) short bfrag;
typedef __attribute__((ext_vector_type(4))) float ffrag;
typedef __attribute__((ext_vector_type(16))) float f16v;

typedef __attribute__((address_space(1))) const unsigned int as1_u32;
typedef __attribute__((address_space(3))) unsigned int as3_u32;

__device__ __forceinline__ ushort f2bf(float f) {
    unsigned u = __builtin_bit_cast(unsigned, f);
    unsigned r = (u + 0x7FFFu + ((u >> 16) & 1u)) >> 16;
    return (ushort)r;
}

__device__ __forceinline__ f16v zero16() {
    f16v z;
    #pragma unroll
    for (int i = 0; i < 16; i++) z[i] = 0.f;
    return z;
}

#define GLD(gp_, lp_) __builtin_amdgcn_global_load_lds((as1_u32*)(gp_), (as3_u32*)(lp_), 16, 0, 0)
#define EXPA(dst_, x_) asm("v_exp_f32 %0, %1" : "=v"(dst_) : "v"(x_))
#define SC_LOG2E 0.18033688011f   /* 0.125 * log2(e) */

// ---------------- fused pre-pass: X build (transpose+emb) AND 4 weight transposes ----------
__global__ void k_pre(const float* __restrict__ hid,
                      const float* __restrict__ Wq, const float* __restrict__ Wk,
                      const float* __restrict__ Wv, const float* __restrict__ Wo,
                      ushort* __restrict__ X,
                      ushort* __restrict__ Wqt, ushort* __restrict__ Wkt,
                      ushort* __restrict__ Wvt, ushort* __restrict__ Wot) {
    __shared__ float t[32][33];
    int tx = threadIdx.x, ty = threadIdx.y;
    int z = blockIdx.z;
    if (z < 2) {
        int b = z;
        int s0 = blockIdx.x * 32, c0 = blockIdx.y * 32;
        if (c0 < 512) {
            t[ty][tx] = hid[((size_t)b * C_ + (c0 + ty)) * S_ + s0 + tx];
            __syncthreads();
            X[((size_t)(b * S_ + s0 + ty)) * QKC_ + c0 + tx] = f2bf(t[tx][ty]);
        } else {
            int c = c0 - 512 + tx;
            int s = s0 + ty;
            int h = s >> 5, w = s & 31;
            float val;
            if (c < 32) {
                int f = c >> 1;
                int n = h * 16 + f;
                float lx = (n == 0) ? -2.0f : log2f((float)n);
                float arg = lx * (float)(f + 1);
                val = (c & 1) ? sinf(arg) : cosf(arg);
            } else {
                int tt = (c - 32) >> 1;
                float theta = ((float)tt + 0.5f) * (float)(w * 16 + tt) * (TWO_PI_ / 512.0f);
                val = (c & 1) ? sinf(theta) : cosf(theta);
            }
            X[(size_t)(b * S_ + s) * QKC_ + c0 + tx] = f2bf(val);
        }
    } else {
        int idx = blockIdx.y * 64 + blockIdx.x;      // 0..1151
        int z4 = idx / 288, rem = idx % 288;
        int k0 = (rem % 18) * 32, n0 = (rem / 18) * 32;
        const float* W; ushort* Wt; int K;
        if (z4 == 0)      { W = Wq; Wt = Wqt; K = QKC_; }
        else if (z4 == 1) { W = Wk; Wt = Wkt; K = QKC_; }
        else if (z4 == 2) { W = Wv; Wt = Wvt; K = C_; }
        else              { W = Wo; Wt = Wot; K = INNER_; }
        if (k0 >= K) return;
        t[ty][tx] = W[(size_t)(k0 + ty) * 512 + n0 + tx];
        __syncthreads();
        Wt[(size_t)(n0 + ty) * K + k0 + tx] = f2bf(t[tx][ty]);
    }
}

// ---------------- fused QKV GEMM (Q pre-scaled by 0.125*log2e) ----------------
#define GSTAGE(buf_, k0_) {                                                   \
    _Pragma("unroll")                                                         \
    for (int i_ = 0; i_ < 6; i_++)                                            \
        GLD(gp[i_] + (k0_), tl + (buf_) * 12288 + lo[i_]); }

__global__ __launch_bounds__(256, 3) void k_qkv(const ushort* __restrict__ X,
                                                const ushort* __restrict__ Wqt,
                                                const ushort* __restrict__ Wkt,
                                                const ushort* __restrict__ Wvt,
                                                ushort* __restrict__ Qb,
                                                ushort* __restrict__ Kpk,
                                                ushort* __restrict__ Vpk) {
    __shared__ ushort __attribute__((aligned(16))) tl[2 * 12288];   // 48 KB

    int tid = threadIdx.x;
    int l = tid & 63, wv = tid >> 6;
    int wr = wv >> 1, wc = wv & 1;
    int bid = blockIdx.x;
    int lgc = (bid & 7) * 96 + (bid >> 3);
    int bx = lgc % 24, by = lgc / 24;
    int n0 = bx * 64, m0 = by * 128;
    int sel = n0 >> 9, n0l = n0 & 511;
    const ushort* Bt = (sel == 0) ? Wqt : (sel == 1) ? Wkt : Wvt;
    const int K = (sel < 2) ? QKC_ : C_;
    const int nst = K >> 6;
    int l15 = l & 15, lg = l >> 4;
    int swz = l15 & 7;

    const ushort* gp[6];
    unsigned lo[6];
    {
        int rsub = l >> 3;
        int clog = (l & 7) ^ rsub;
        #pragma unroll
        for (int i = 0; i < 6; i++) {
            int c = wv * 6 + i;
            lo[i] = c * 512;
            if (c < 16) gp[i] = X  + (size_t)(m0  + c * 8        + rsub) * QKC_ + clog * 8;
            else        gp[i] = Bt + (size_t)(n0l + (c - 16) * 8 + rsub) * K    + clog * 8;
        }
    }

    ffrag acc[4][2];
    #pragma unroll
    for (int i = 0; i < 4; i++)
        #pragma unroll
        for (int j = 0; j < 2; j++) acc[i][j] = (ffrag){0.f, 0.f, 0.f, 0.f};

    GSTAGE(0, 0);
    int cur = 0;
    for (int kt = 0; kt < nst; kt++) {
        __syncthreads();
        if (kt + 1 < nst) GSTAGE(cur ^ 1, (kt + 1) * 64);
        const ushort* As = tl + cur * 12288;
        const ushort* Bs = As + 8192;
        #pragma unroll
        for (int ks = 0; ks < 2; ks++) {
            int cl = ks * 4 + lg;
            int ch = (cl ^ swz) * 8;
            bfrag af[4], bf[2];
            #pragma unroll
            for (int mi = 0; mi < 4; mi++)
                af[mi] = *(const bfrag*)(As + (wr * 64 + mi * 16 + l15) * 64 + ch);
            #pragma unroll
            for (int nj = 0; nj < 2; nj++)
                bf[nj] = *(const bfrag*)(Bs + (wc * 32 + nj * 16 + l15) * 64 + ch);
            #pragma unroll
            for (int mi = 0; mi < 4; mi++)
                #pragma unroll
                for (int nj = 0; nj < 2; nj++)
                    acc[mi][nj] = __builtin_amdgcn_mfma_f32_16x16x32_bf16(af[mi], bf[nj], acc[mi][nj], 0, 0, 0);
        }
        cur ^= 1;
    }

    if (sel == 0) {
        #pragma unroll
        for (int mi = 0; mi < 4; mi++)
            #pragma unroll
            for (int nj = 0; nj < 2; nj++)
                #pragma unroll
                for (int r = 0; r < 4; r++) {
                    int row = m0 + wr * 64 + mi * 16 + lg * 4 + r;
                    int col = n0l + wc * 32 + nj * 16 + l15;
                    Qb[(size_t)row * INNER_ + col] = f2bf(acc[mi][nj][r] * SC_LOG2E);
                }
    } else {
        ushort (*Ct)[136] = (ushort(*)[136])tl;
        __syncthreads();
        #pragma unroll
        for (int mi = 0; mi < 4; mi++)
            #pragma unroll
            for (int nj = 0; nj < 2; nj++)
                #pragma unroll
                for (int r = 0; r < 4; r++)
                    Ct[wc * 32 + nj * 16 + l15][wr * 64 + mi * 16 + lg * 4 + r] = f2bf(acc[mi][nj][r]);
        __syncthreads();
        int pair = (m0 >> 11) * 8 + (n0l >> 6);
        int kvb0 = (m0 & 2047) >> 5;
        if (sel == 1) {
            #pragma unroll
            for (int p = 0; p < 4; p++) {
                int cid = tid + p * 256;
                int sl = cid >> 7, kv = cid & 127;
                bfrag tmp;
                #pragma unroll
                for (int j = 0; j < 8; j++) tmp[j] = (short)Ct[sl * 8 + j][kv];
                ushort* dst = Kpk + ((size_t)((pair * 64 + kvb0 + (kv >> 5)) * 8 + sl)) * 256 + (kv & 31) * 8;
                *(uint4*)dst = __builtin_bit_cast(uint4, tmp);
            }
        } else {
            #pragma unroll
            for (int p = 0; p < 4; p++) {
                int cid = tid + p * 256;
                int d = cid >> 4, mc = cid & 15;
                uint4 v = *(uint4*)&Ct[d][mc * 8];
                ushort* dst = Vpk + ((size_t)((pair * 64 + kvb0 + (mc >> 2)) * 4 + (mc & 3))) * 512 + d * 8;
                *(uint4*)dst = v;
            }
        }
    }
}

// ---------------- output GEMM + bias + transpose + residual ----------------
__global__ __launch_bounds__(256, 2) void k_og(const ushort* __restrict__ Ob,
                                               const ushort* __restrict__ Wot,
                                               const float* __restrict__ bias,
                                               const float* __restrict__ hid,
                                               float* __restrict__ out) {
    __shared__ ushort __attribute__((aligned(16))) tl[2 * 12288];

    int tid = threadIdx.x;
    int l = tid & 63, wv = tid >> 6;
    int wr = wv >> 1, wc = wv & 1;
    int bid = blockIdx.x;
    int lgc = (bid & 7) * 32 + (bid >> 3);
    int bx = lgc & 7, by = lgc >> 3;
    int n0 = bx * 64, m0 = by * 128;
    int l15 = l & 15, lg = l >> 4;
    int swz = l15 & 7;

    const ushort* gp[6];
    unsigned lo[6];
    {
        int rsub = l >> 3;
        int clog = (l & 7) ^ rsub;
        #pragma unroll
        for (int i = 0; i < 6; i++) {
            int c = wv * 6 + i;
            lo[i] = c * 512;
            if (c < 16) gp[i] = Ob  + (size_t)(m0 + c * 8        + rsub) * INNER_ + clog * 8;
            else        gp[i] = Wot + (size_t)(n0 + (c - 16) * 8 + rsub) * INNER_ + clog * 8;
        }
    }

    ffrag acc[4][2];
    #pragma unroll
    for (int i = 0; i < 4; i++)
        #pragma unroll
        for (int j = 0; j < 2; j++) acc[i][j] = (ffrag){0.f, 0.f, 0.f, 0.f};

    GSTAGE(0, 0);
    int cur = 0;
    for (int kt = 0; kt < 8; kt++) {
        __syncthreads();
        if (kt < 7) GSTAGE(cur ^ 1, (kt + 1) * 64);
        const ushort* As = tl + cur * 12288;
        const ushort* Bs = As + 8192;
        #pragma unroll
        for (int ks = 0; ks < 2; ks++) {
            int cl = ks * 4 + lg;
            int ch = (cl ^ swz) * 8;
            bfrag af[4], bf[2];
            #pragma unroll
            for (int mi = 0; mi < 4; mi++)
                af[mi] = *(const bfrag*)(As + (wr * 64 + mi * 16 + l15) * 64 + ch);
            #pragma unroll
            for (int nj = 0; nj < 2; nj++)
                bf[nj] = *(const bfrag*)(Bs + (wc * 32 + nj * 16 + l15) * 64 + ch);
            #pragma unroll
            for (int mi = 0; mi < 4; mi++)
                #pragma unroll
                for (int nj = 0; nj < 2; nj++)
                    acc[mi][nj] = __builtin_amdgcn_mfma_f32_16x16x32_bf16(af[mi], bf[nj], acc[mi][nj], 0, 0, 0);
        }
        cur ^= 1;
    }

    float (*Cf)[129] = (float(*)[129])tl;
    float bv[2];
    #pragma unroll
    for (int nj = 0; nj < 2; nj++) bv[nj] = bias[n0 + wc * 32 + nj * 16 + l15];
    __syncthreads();
    #pragma unroll
    for (int mi = 0; mi < 4; mi++)
        #pragma unroll
        for (int nj = 0; nj < 2; nj++)
            #pragma unroll
            for (int r = 0; r < 4; r++)
                Cf[wc * 32 + nj * 16 + l15][wr * 64 + mi * 16 + lg * 4 + r] = acc[mi][nj][r] + bv[nj];
    __syncthreads();
    int b = m0 >> 11, s0m = m0 & 2047;
    #pragma unroll
    for (int p = 0; p < 8; p++) {
        int f = p * 256 + tid;
        int c = f >> 5, sq = (f & 31) * 4;
        size_t o = (((size_t)(b * 512 + n0 + c)) << 11) + s0m + sq;
        float4 hv = *(const float4*)(hid + o);
        float4 cv = *(float4*)&Cf[c][sq];
        cv.x += hv.x; cv.y += hv.y; cv.z += hv.z; cv.w += hv.w;
        *(float4*)(out + o) = cv;
    }
}

// ---------------- flash attention: round-12 best (register-prefetched, max-free) --------
// grid 256 x 512 thr = 8 waves: (qi 0..1) x (sp 0..3). Wave owns 64 q rows (dual group)
// and a quarter KV stream; K/V fragments in registers with unroll-2 prefetch; softmax is
// max-free (pre-scaled Q, bare v_exp); concurrent-dump epilogue.
#define CVTPK(dst, a, b) asm("v_cvt_pk_bf16_f32 %0, %1, %2" : "=v"(dst) : "v"(a), "v"(b))
#define SWAP32(a, b)     asm("v_permlane32_swap_b32 %0, %1" : "+v"(a), "+v"(b))

#define KLOAD(dst_, kt_) {                                                    \
    const ushort* g_ = kpb + (size_t)(kt_) * 2048 + kro;                      \
    _Pragma("unroll")                                                         \
    for (int ks_ = 0; ks_ < 4; ks_++) dst_[ks_] = *(const bfrag*)(g_ + ks_ * 512); }

#define VLOAD(dst_, kt_) {                                                    \
    const ushort* g_ = vpb + (size_t)(kt_) * 2048 + vro;                      \
    dst_[0] = *(const bfrag*)(g_);                                            \
    dst_[1] = *(const bfrag*)(g_ + 256);                                      \
    dst_[2] = *(const bfrag*)(g_ + 1024);                                     \
    dst_[3] = *(const bfrag*)(g_ + 1280); }

#define PVHALF(sf_, vf_, a0_, a1_) {                                          \
    _Pragma("unroll")                                                         \
    for (int s = 0; s < 2; s++) {                                             \
        unsigned A0, B0, A1, B1;                                              \
        CVTPK(A0, sf_[s * 8 + 0], sf_[s * 8 + 1]); CVTPK(B0, sf_[s * 8 + 4], sf_[s * 8 + 5]); \
        SWAP32(A0, B0);                                                       \
        CVTPK(A1, sf_[s * 8 + 2], sf_[s * 8 + 3]); CVTPK(B1, sf_[s * 8 + 6], sf_[s * 8 + 7]); \
        SWAP32(A1, B1);                                                       \
        uint4 u_; u_.x = A0; u_.y = A1; u_.z = B0; u_.w = B1;                 \
        bfrag pa_ = __builtin_bit_cast(bfrag, u_);                            \
        a0_ = __builtin_amdgcn_mfma_f32_32x32x16_bf16(vf_[s * 2],     pa_, a0_, 0, 0, 0); \
        a1_ = __builtin_amdgcn_mfma_f32_32x32x16_bf16(vf_[s * 2 + 1], pa_, a1_, 0, 0, 0); \
    } }

#define ABODY(kf_, vf_) {                                                     \
    __builtin_amdgcn_s_setprio(1);                                            \
    f16v sfA = __builtin_amdgcn_mfma_f32_32x32x16_bf16(kf_[0], qfA[0], fz, 0, 0, 0); \
    f16v sfB = __builtin_amdgcn_mfma_f32_32x32x16_bf16(kf_[0], qfB[0], fz, 0, 0, 0); \
    _Pragma("unroll")                                                         \
    for (int ks = 1; ks < 4; ks++) {                                          \
        sfA = __builtin_amdgcn_mfma_f32_32x32x16_bf16(kf_[ks], qfA[ks], sfA, 0, 0, 0); \
        sfB = __builtin_amdgcn_mfma_f32_32x32x16_bf16(kf_[ks], qfB[ks], sfB, 0, 0, 0); \
    }                                                                         \
    __builtin_amdgcn_s_setprio(0);                                            \
    float a0 = 0.f, a1 = 0.f, a2 = 0.f, a3 = 0.f;                             \
    float b0 = 0.f, b1 = 0.f, b2 = 0.f, b3 = 0.f;                             \
    _Pragma("unroll")                                                         \
    for (int j = 0; j < 4; j++) {                                             \
        float pA0; EXPA(pA0, sfA[j]);      sfA[j] = pA0;      a0 += pA0;      \
        float pA1; EXPA(pA1, sfA[j + 4]);  sfA[j + 4] = pA1;  a1 += pA1;      \
        float pA2; EXPA(pA2, sfA[j + 8]);  sfA[j + 8] = pA2;  a2 += pA2;      \
        float pA3; EXPA(pA3, sfA[j + 12]); sfA[j + 12] = pA3; a3 += pA3;      \
        float pB0; EXPA(pB0, sfB[j]);      sfB[j] = pB0;      b0 += pB0;      \
        float pB1; EXPA(pB1, sfB[j + 4]);  sfB[j + 4] = pB1;  b1 += pB1;      \
        float pB2; EXPA(pB2, sfB[j + 8]);  sfB[j + 8] = pB2;  b2 += pB2;      \
        float pB3; EXPA(pB3, sfB[j + 12]); sfB[j + 12] = pB3; b3 += pB3;      \
    }                                                                         \
    lA += (a0 + a1) + (a2 + a3);                                              \
    lB += (b0 + b1) + (b2 + b3);                                              \
    __builtin_amdgcn_s_setprio(1);                                            \
    PVHALF(sfA, vf_, accA0, accA1);                                           \
    PVHALF(sfB, vf_, accB0, accB1);                                           \
    __builtin_amdgcn_s_setprio(0); }

__global__ __launch_bounds__(512, 2) void k_attn(const ushort* __restrict__ Qf,
                                                 const ushort* __restrict__ Kpk,
                                                 const ushort* __restrict__ Vpk,
                                                 ushort* __restrict__ Ob) {
    __shared__ __attribute__((aligned(16))) char smem[137216];
    float* cmb = (float*)smem;                   // [8 waves][2 g][2112] f32 = 135168 B
    float* lsh = (float*)(smem + 135168);        // [8 waves][2 g][32]

    const int id  = blockIdx.x;                  // 0..255
    const int xcd = id & 7, wi = id >> 3;
    const int pair = xcd * 2 + (wi >> 4);
    const int qt   = wi & 15;
    const int hd = pair & 7, b = pair >> 3;

    const int tid = threadIdx.x;
    const int l = tid & 63, wvid = tid >> 6;
    const int qi = wvid >> 2, sp = wvid & 3;
    const int l31 = l & 31, hi = l >> 5;
    const int hoff = hd * HD_;
    const int brow = b * S_ + qt * 128;

    bfrag qfA[4], qfB[4];
    {
        const ushort* qpA = Qf + (size_t)(brow + qi * 64 + l31) * INNER_ + hoff + hi * 8;
        const ushort* qpB = qpA + (size_t)32 * INNER_;
        #pragma unroll
        for (int ks = 0; ks < 4; ks++) {
            qfA[ks] = *(const bfrag*)(qpA + ks * 16);
            qfB[ks] = *(const bfrag*)(qpB + ks * 16);
        }
    }

    const ushort* kpb = Kpk + ((size_t)pair * 64 + sp * 16) * 2048;
    const ushort* vpb = Vpk + ((size_t)pair * 64 + sp * 16) * 2048;
    const int kro = hi * 256 + l31 * 8;
    const int vro = hi * 512 + l31 * 8;

    const f16v fz = zero16();
    float lA = 0.f, lB = 0.f;
    f16v accA0 = fz, accA1 = fz;
    f16v accB0 = fz, accB1 = fz;

    bfrag kc[4], vc[4], kn[4], vn[4];
    KLOAD(kc, 0); VLOAD(vc, 0);

    for (int it = 0; it < 16; it += 2) {
        if (it + 1 < 16) { KLOAD(kn, it + 1); VLOAD(vn, it + 1); }
        ABODY(kc, vc);
        if (it + 2 < 16) { KLOAD(kc, it + 2); VLOAD(vc, it + 2); }
        ABODY(kn, vn);
    }

    lA += __shfl_xor(lA, 32);
    lB += __shfl_xor(lB, 32);

    if (hi == 0) {
        lsh[(wvid * 2 + 0) * 32 + l31] = lA;
        lsh[(wvid * 2 + 1) * 32 + l31] = lB;
    }
    {
        float* cA = cmb + (wvid * 2 + 0) * 2112;
        float* cB = cmb + (wvid * 2 + 1) * 2112;
        #pragma unroll
        for (int j = 0; j < 16; j++) {
            int d0 = (j & 3) + 8 * (j >> 2) + 4 * hi;
            cA[d0 * 33 + l31]        = accA0[j];
            cA[(d0 + 32) * 33 + l31] = accA1[j];
            cB[d0 * 33 + l31]        = accB0[j];
            cB[(d0 + 32) * 33 + l31] = accB1[j];
        }
    }
    __syncthreads();
    #pragma unroll
    for (int p2 = 0; p2 < 2; p2++) {
        int f = p2 * 512 + tid;                  // [4 qig][32 q][8 dc]
        int qig = f >> 8;
        int t2 = f & 255;
        int qq = t2 >> 3, cc = t2 & 7;
        int qih = qig >> 1, g = qig & 1;
        float lt = 0.f;
        #pragma unroll
        for (int s4 = 0; s4 < 4; s4++) lt += lsh[((qih * 4 + s4) * 2 + g) * 32 + qq];
        float inv = 1.0f / lt;
        bfrag ov;
        #pragma unroll
        for (int j = 0; j < 8; j++) {
            int d = cc * 8 + j;
            float s = 0.f;
            #pragma unroll
            for (int s4 = 0; s4 < 4; s4++)
                s += cmb[((qih * 4 + s4) * 2 + g) * 2112 + d * 33 + qq];
            ov[j] = (short)f2bf(s * inv);
        }
        *(uint4*)(Ob + (size_t)(brow + qig * 32 + qq) * INNER_ + hoff + cc * 8) = __builtin_bit_cast(uint4, ov);
    }
}

extern "C" void kernel_launch(void* const* d_in, const int* in_sizes, int n_in,
                              void* d_out, int out_size, void* d_ws, size_t ws_size,
                              hipStream_t stream) {
    const float* hid  = (const float*)d_in[0];
    const float* Wq   = (const float*)d_in[1];
    const float* Wk   = (const float*)d_in[2];
    const float* Wv   = (const float*)d_in[3];
    const float* Wout = (const float*)d_in[4];
    const float* bout = (const float*)d_in[5];
    float* out = (float*)d_out;

    const int M = B_ * S_;   // 4096
    char* w = (char*)d_ws;
    ushort* X    = (ushort*)w;                    w += (size_t)M * QKC_ * 2;
    ushort* Qb   = (ushort*)w;                    w += (size_t)M * INNER_ * 2;
    ushort* Kpk  = (ushort*)w;                    w += (size_t)M * INNER_ * 2;   // packed
    ushort* Vpk  = (ushort*)w;                    w += (size_t)M * INNER_ * 2;   // packed
    ushort* Ob   = (ushort*)w;                    w += (size_t)M * INNER_ * 2;
    ushort* Wqt  = (ushort*)w;                    w += (size_t)INNER_ * QKC_ * 2;
    ushort* Wkt  = (ushort*)w;                    w += (size_t)INNER_ * QKC_ * 2;
    ushort* Wvt  = (ushort*)w;                    w += (size_t)INNER_ * C_ * 2;
    ushort* Wot  = (ushort*)w;                    w += (size_t)C_ * INNER_ * 2;

    k_pre<<<dim3(64, 18, 3), dim3(32, 32), 0, stream>>>(hid, Wq, Wk, Wv, Wout,
                                                        X, Wqt, Wkt, Wvt, Wot);

    k_qkv<<<dim3(768), 256, 0, stream>>>(X, Wqt, Wkt, Wvt, Qb, Kpk, Vpk);

    k_attn<<<dim3(256), 512, 0, stream>>>(Qb, Kpk, Vpk, Ob);

    k_og<<<dim3(256), 256, 0, stream>>>(Ob, Wot, bout, hid, out);
}